// Round 14
// baseline (63.749 us; speedup 1.0000x reference)
//
#include <hip/hip_runtime.h>
#include <hip/hip_bf16.h>
#include <math.h>

#define B_ 4
#define S_ 2048
#define D_ 256
#define H_ 8
#define HD_ 32

typedef __attribute__((ext_vector_type(8))) short short8;
typedef __attribute__((ext_vector_type(4))) short short4v;
typedef __attribute__((ext_vector_type(4))) float floatx4;
typedef unsigned short ushort_t;
typedef unsigned int uint_t;

typedef union { unsigned u[2]; short4v v4; } PkU;

// v_cvt_pk_bf16_f32: pack 2 fp32 -> 2 bf16 (RNE), one instruction
#define CVT_PK(DST, LO, HI) \
  asm volatile("v_cvt_pk_bf16_f32 %0, %1, %2" : "=v"(DST) : "v"(LO), "v"(HI))

// D = A * B + D  (16x16x16 bf16 -> fp32 acc). Volatile: source order IS the
// emitted order. asm->asm VALU-write -> MFMA-read needs >=2 instr distance
// (round-6 lesson) -- honored by the 2-slot-lookahead pipeline below.
#define MFMA16(ACC, A, B) \
  asm volatile("v_mfma_f32_16x16x16_bf16 %0, %1, %2, %0" : "+v"(ACC) : "v"(A), "v"(B))

// round-to-nearest-even fp32 -> bf16 (scalar path)
__device__ __forceinline__ ushort_t f2bf(float f) {
  union { float f; unsigned u; } v; v.f = f;
  unsigned u = v.u;
  unsigned r = (u + 0x7FFFu + ((u >> 16) & 1u)) >> 16;
  return (ushort_t)r;
}

// fused fp32->bf16 conversion for x + all 4 weight matrices (one launch)
__global__ __launch_bounds__(256)
void cvt_all(const float* __restrict__ x,
             const float* __restrict__ wq, const float* __restrict__ wk,
             const float* __restrict__ wv, const float* __restrict__ wo,
             ushort_t* __restrict__ xb,
             ushort_t* __restrict__ wqb, ushort_t* __restrict__ wkb,
             ushort_t* __restrict__ wvb, ushort_t* __restrict__ wob)
{
  const int b = blockIdx.x;
  const float4* s; uint2* d; int i;
  if (b < 2048) {                       // x: 2M elems = 524288 float4
    s = (const float4*)x; d = (uint2*)xb; i = b * 256 + threadIdx.x;
  } else {                              // 4 weights: 16384 float4 each
    int r = b - 2048; int mm = r >> 6;
    s = (const float4*)(mm == 0 ? wq : mm == 1 ? wk : mm == 2 ? wv : wo);
    d = (uint2*)(mm == 0 ? wqb : mm == 1 ? wkb : mm == 2 ? wvb : wob);
    i = (r & 63) * 256 + threadIdx.x;
  }
  float4 f = s[i];
  uint2 o;
  CVT_PK(o.x, f.x, f.y);
  CVT_PK(o.y, f.z, f.w);
  d[i] = o;
}

// C = X @ W^T + b for Q,K,V (bf16). 128 rows/block; W-tile staged in LDS.
// Q pre-scaled by log2(e)/sqrt(Hd). Q,K -> (B,H,S,Hd); V -> TRANSPOSED (B,H,Hd,S).
__global__ __launch_bounds__(256)
void proj_qkv(const ushort_t* __restrict__ xb,
              const ushort_t* __restrict__ wq, const ushort_t* __restrict__ wk, const ushort_t* __restrict__ wv,
              const float* __restrict__ bq, const float* __restrict__ bk, const float* __restrict__ bv,
              ushort_t* __restrict__ qout, ushort_t* __restrict__ kout, ushort_t* __restrict__ vout)
{
  __shared__ __align__(16) ushort_t W_lds[64 * 264];   // 64 cols x 256 k, pad 264

  const int z = blockIdx.z;
  const ushort_t* wb = (z == 0) ? wq : (z == 1) ? wk : wv;
  const float* bias  = (z == 0) ? bq : (z == 1) ? bk : bv;

  const int t = threadIdx.x;
  const int l = t & 63;
  const int w = t >> 6;
  const int row0 = blockIdx.y * 128 + w * 16;   // rows row0 and row0+64
  const int col0 = blockIdx.x * 64;
  const int lr = l & 15, lg = l >> 4, lk = lg * 8;

  // ---- stage W-tile: thread t loads 128 B of row (t>>2) ----
  {
    const ushort_t* wsrc = wb + (col0 + (t >> 2)) * D_ + (t & 3) * 64;
    ushort_t* wdst = &W_lds[(t >> 2) * 264 + (t & 3) * 64];
#pragma unroll
    for (int i = 0; i < 8; ++i)
      *(uint4*)(wdst + i * 8) = *(const uint4*)(wsrc + i * 8);
  }
  __syncthreads();

  floatx4 acc[2][4] = {};
  const ushort_t* arow0 = xb + (row0 + lr) * D_ + lk;
  const ushort_t* arow1 = xb + (row0 + 64 + lr) * D_ + lk;
#pragma unroll
  for (int kk = 0; kk < D_; kk += 32) {
    short8 a0 = *(const short8*)(arow0 + kk);
    short8 a1 = *(const short8*)(arow1 + kk);
#pragma unroll
    for (int j = 0; j < 4; ++j) {
      short8 b = *(const short8*)&W_lds[(j * 16 + lr) * 264 + kk + lk];
      acc[0][j] = __builtin_amdgcn_mfma_f32_16x16x32_bf16(a0, b, acc[0][j], 0, 0, 0);
      acc[1][j] = __builtin_amdgcn_mfma_f32_16x16x32_bf16(a1, b, acc[1][j], 0, 0, 0);
    }
  }

  if (z == 2) {
    // V^T: (B,H,Hd,S); acc rows r -> consecutive s -> vectorized 8B store
#pragma unroll
    for (int rs = 0; rs < 2; ++rs)
#pragma unroll
      for (int j = 0; j < 4; ++j) {
        int c = col0 + j * 16 + lr;
        float bv_ = bias[c];
        int hh = c >> 5, d = c & 31;
        int i0 = row0 + rs * 64 + lg * 4;
        int bb = i0 >> 11, s0 = i0 & 2047;
        uint2 pv;
        CVT_PK(pv.x, acc[rs][j][0] + bv_, acc[rs][j][1] + bv_);
        CVT_PK(pv.y, acc[rs][j][2] + bv_, acc[rs][j][3] + bv_);
        *(uint2*)&vout[(((size_t)(bb * H_ + hh)) * HD_ + d) * S_ + s0] = pv;
      }
  } else {
    ushort_t* dst = (z == 0) ? qout : kout;
    const float qscale = (z == 0) ? 0.25503486f : 1.0f;  // log2(e)/sqrt(32)
#pragma unroll
    for (int rs = 0; rs < 2; ++rs)
#pragma unroll
      for (int j = 0; j < 4; ++j) {
        int c = col0 + j * 16 + lr;
        float bv_ = bias[c];
        int hh = c >> 5, d = c & 31;
#pragma unroll
        for (int rp = 0; rp < 2; ++rp) {
          int i = row0 + rs * 64 + lg * 4 + rp * 2;
          int bb = i >> 11, s = i & 2047;
          uint_t pr;
          CVT_PK(pr, (acc[rs][j][rp*2] + bv_) * qscale, (acc[rs][j][rp*2+1] + bv_) * qscale);
          size_t b0 = ((size_t)(bb * H_ + hh) * S_ + s) * HD_ + d;
          dst[b0]       = (ushort_t)(pr & 0xffffu);
          dst[b0 + HD_] = (ushort_t)(pr >> 16);
        }
      }
  }
}

// flash attention, no-max softmax, SPLIT-K over the KV stream: each (bh,qt)
// is computed by 2 blocks covering S/2 each -> grid 1024 x 512thr = 4
// blocks/CU = 2x occupancy (r13 was latency-bound at 2 blocks/CU). No-max
// softmax makes partials combine by PURE ADDITION (no rescale). Per-wave
// tile body identical to the proven r9/r10/r13 pipeline.
__global__ __launch_bounds__(512)
void attn_kernel(const ushort_t* __restrict__ qb, const ushort_t* __restrict__ kb,
                 const ushort_t* __restrict__ vtb,
                 float* __restrict__ opart, float* __restrict__ lpart)
{
  __shared__ __align__(16) ushort_t K_lds[2][128 * 40];   // [k][d] stride 40 (2-way free)
  __shared__ __align__(16) ushort_t Vt_lds[2][32 * 140];  // [d][k] stride 140 (2-way free)

  const int tid = threadIdx.x;
  const int l = tid & 63;
  const int w = tid >> 6;                      // 0..7
  // XCD swizzle: linear block id f; f%8 = XCD under round-robin dispatch.
  // Both halves of a (bh,qt) share f%8 -> same XCD -> K/V L2-resident.
  const int f = blockIdx.y * 32 + blockIdx.x;  // 0..1023
  const int half = f >> 9;                     // 0..1 (KV-stream half)
  const int rem = f & 511;
  const int qt = rem >> 5;                     // 0..15 (128-row q tiles)
  const int bh = (rem & 7) * 4 + ((rem >> 3) & 3); // 0..31
  const int lr = l & 15;
  const int lg = l >> 4;

  const ushort_t* qp  = qb  + (size_t)bh * S_ * HD_;
  const ushort_t* kp  = kb  + (size_t)bh * S_ * HD_;
  const ushort_t* vtp = vtb + (size_t)bh * S_ * HD_;   // (Hd,S)

  const int q0 = qt * 128 + w * 16;
  short8 qfrag = *(const short8*)(qp + (q0 + lr) * HD_ + lg * 8);

  floatx4 oA = {}, oB = {}, oL = {};   // O^T accs + lsum acc (oL[0] meaningful)

  const int kr = tid >> 2, kc = (tid & 3) * 8;    // K staging: 128 rows x 32, 1 uint4/thr
  const int vr = tid >> 4, vc = (tid & 15) * 8;   // V^T staging: 32 rows x 128, 1 uint4/thr

  const short4v ones4 = {0x3F80, 0x3F80, 0x3F80, 0x3F80};  // bf16 1.0
  const floatx4 zero4 = {0.f, 0.f, 0.f, 0.f};

  const int t_begin = half << 10;              // 0 or 1024
  const int t_end   = t_begin + 1024;

  // prologue: stage first tile of this half
  uint4 kreg = *(const uint4*)(kp + (t_begin + kr) * HD_ + kc);
  uint4 vreg = *(const uint4*)(vtp + vr * S_ + t_begin + vc);
  *(uint4*)&K_lds[0][kr * 40 + kc] = kreg;
  {
    ushort_t* vd = &Vt_lds[0][vr * 140 + vc];   // row base 280B: 8B-aligned
    *(uint2*)(vd)     = make_uint2(vreg.x, vreg.y);
    *(uint2*)(vd + 4) = make_uint2(vreg.z, vreg.w);
  }

  int cur = 0;
  for (int t0 = t_begin; t0 < t_end; t0 += 128) {
    __syncthreads();   // staged tile visible; everyone done reading buf^1

    // prefetch next tile into regs (wraps within half on last iter)
    int tn = t0 + 128; if (tn == t_end) tn = t_begin;
    kreg = *(const uint4*)(kp + (tn + kr) * HD_ + kc);
    vreg = *(const uint4*)(vtp + vr * S_ + tn + vc);

    // ---- QK^T swapped, C=0: sv[s] = scores (log2 domain), 8 indep chains ----
    floatx4 sv[8];
#pragma unroll
    for (int s = 0; s < 8; ++s) {
      short8 kf = *(const short8*)&K_lds[cur][(s * 16 + lr) * 40 + lg * 8];
      sv[s] = __builtin_amdgcn_mfma_f32_16x16x32_bf16(kf, qfrag, zero4, 0, 0, 0);
    }

    // ---- software-pipelined softmax+PV (2-slot lookahead) ----
    PkU pk[8];
    __builtin_amdgcn_s_setprio(1);
    // pipeline prologue: slots 0,1 exp+pack
#pragma unroll
    for (int s = 0; s < 2; ++s) {
      sv[s][0] = __builtin_amdgcn_exp2f(sv[s][0]);
      sv[s][1] = __builtin_amdgcn_exp2f(sv[s][1]);
      sv[s][2] = __builtin_amdgcn_exp2f(sv[s][2]);
      sv[s][3] = __builtin_amdgcn_exp2f(sv[s][3]);
    }
    CVT_PK(pk[0].u[0], sv[0][0], sv[0][1]);
    CVT_PK(pk[0].u[1], sv[0][2], sv[0][3]);
    CVT_PK(pk[1].u[0], sv[1][0], sv[1][1]);
    CVT_PK(pk[1].u[1], sv[1][2], sv[1][3]);
    // steady state: PV(s) interleaved with exp/pack(s+2)
#pragma unroll
    for (int s = 0; s < 8; ++s) {
      const int cb = s * 16 + lg * 4;
      short4v a0 = *(const short4v*)&Vt_lds[cur][lr * 140 + cb];
      short4v a1 = *(const short4v*)&Vt_lds[cur][(16 + lr) * 140 + cb];
      MFMA16(oA, a0, pk[s].v4);
      MFMA16(oB, a1, pk[s].v4);
      MFMA16(oL, ones4, pk[s].v4);
      if (s + 2 < 8) {
        sv[s+2][0] = __builtin_amdgcn_exp2f(sv[s+2][0]);
        sv[s+2][1] = __builtin_amdgcn_exp2f(sv[s+2][1]);
        sv[s+2][2] = __builtin_amdgcn_exp2f(sv[s+2][2]);
        sv[s+2][3] = __builtin_amdgcn_exp2f(sv[s+2][3]);
        CVT_PK(pk[s+2].u[0], sv[s+2][0], sv[s+2][1]);
        CVT_PK(pk[s+2].u[1], sv[s+2][2], sv[s+2][3]);
      }
    }
    __builtin_amdgcn_s_setprio(0);

    // ---- store prefetched regs into the other buffer ----
    *(uint4*)&K_lds[cur ^ 1][kr * 40 + kc] = kreg;
    {
      ushort_t* vd = &Vt_lds[cur ^ 1][vr * 140 + vc];
      *(uint2*)(vd)     = make_uint2(vreg.x, vreg.y);
      *(uint2*)(vd + 4) = make_uint2(vreg.z, vreg.w);
    }
    cur ^= 1;
  }

  asm volatile("s_nop 7\n\ts_nop 7" :::);   // MFMA->VALU/VMEM hazard guard
  // ---- write fp32 partials (unnormalized O sums + lsum); combine adds ----
  const size_t prow = ((size_t)(half * 32 + bh)) * S_ + q0 + lr;
  *(floatx4*)&opart[prow * 32 + lg * 4]      = oA;
  *(floatx4*)&opart[prow * 32 + 16 + lg * 4] = oB;
  if (lg == 0) lpart[prow] = oL[0];
}

// combine: Hctx = (O0+O1) * head_scale / (l0+l1), bf16 out (B,S,D)
__global__ __launch_bounds__(256)
void combine(const float* __restrict__ opart, const float* __restrict__ lpart,
             const float* __restrict__ head_scale, ushort_t* __restrict__ hb)
{
  const int idx = blockIdx.x * 256 + threadIdx.x;   // 262144 = 65536 rows x 4
  const int row = idx >> 2;            // bh*2048 + s
  const int c8  = (idx & 3) * 8;       // d chunk of 8
  const float* o0 = opart + (size_t)row * 32 + c8;
  const float* o1 = opart + ((size_t)(65536 + row)) * 32 + c8;
  const float lsum = lpart[row] + lpart[65536 + row];
  const int bh = row >> 11, hh = bh & 7, bb = bh >> 3, s = row & 2047;
  const float inv = head_scale[hh] / lsum;
  float4 a0 = *(const float4*)o0, b0 = *(const float4*)(o0 + 4);
  float4 a1 = *(const float4*)o1, b1 = *(const float4*)(o1 + 4);
  uint4 w;
  CVT_PK(w.x, (a0.x + a1.x) * inv, (a0.y + a1.y) * inv);
  CVT_PK(w.y, (a0.z + a1.z) * inv, (a0.w + a1.w) * inv);
  CVT_PK(w.z, (b0.x + b1.x) * inv, (b0.y + b1.y) * inv);
  CVT_PK(w.w, (b0.z + b1.z) * inv, (b0.w + b1.w) * inv);
  *(uint4*)&hb[((size_t)(bb * S_ + s)) * D_ + hh * HD_ + c8] = w;
}

// out = Hctx @ Wo^T + bo  (128 rows/block; Wo-tile staged in LDS, fp32 out)
__global__ __launch_bounds__(256)
void proj_out(const ushort_t* __restrict__ hbm, const ushort_t* __restrict__ wo,
              const float* __restrict__ bo, float* __restrict__ out)
{
  __shared__ __align__(16) ushort_t W_lds[64 * 264];

  const int t = threadIdx.x;
  const int l = t & 63;
  const int w = t >> 6;
  const int row0 = blockIdx.y * 128 + w * 16;   // rows row0 and row0+64
  const int col0 = blockIdx.x * 64;
  const int lr = l & 15, lg = l >> 4, lk = lg * 8;

  {
    const ushort_t* wsrc = wo + (col0 + (t >> 2)) * D_ + (t & 3) * 64;
    ushort_t* wdst = &W_lds[(t >> 2) * 264 + (t & 3) * 64];
#pragma unroll
    for (int i = 0; i < 8; ++i)
      *(uint4*)(wdst + i * 8) = *(const uint4*)(wsrc + i * 8);
  }
  __syncthreads();

  floatx4 acc[2][4] = {};
  const ushort_t* arow0 = hbm + (row0 + lr) * D_ + lk;
  const ushort_t* arow1 = hbm + (row0 + 64 + lr) * D_ + lk;
#pragma unroll
  for (int kk = 0; kk < D_; kk += 32) {
    short8 a0 = *(const short8*)(arow0 + kk);
    short8 a1 = *(const short8*)(arow1 + kk);
#pragma unroll
    for (int j = 0; j < 4; ++j) {
      short8 b = *(const short8*)&W_lds[(j * 16 + lr) * 264 + kk + lk];
      acc[0][j] = __builtin_amdgcn_mfma_f32_16x16x32_bf16(a0, b, acc[0][j], 0, 0, 0);
      acc[1][j] = __builtin_amdgcn_mfma_f32_16x16x32_bf16(a1, b, acc[1][j], 0, 0, 0);
    }
  }
#pragma unroll
  for (int rs = 0; rs < 2; ++rs)
#pragma unroll
    for (int j = 0; j < 4; ++j) {
      int c = col0 + j * 16 + lr;
      float bias = bo[c];
#pragma unroll
      for (int r = 0; r < 4; ++r) {
        int i = row0 + rs * 64 + lg * 4 + r;
        out[(size_t)i * D_ + c] = acc[rs][j][r] + bias;
      }
    }
}

extern "C" void kernel_launch(void* const* d_in, const int* in_sizes, int n_in,
                              void* d_out, int out_size, void* d_ws, size_t ws_size,
                              hipStream_t stream) {
  (void)in_sizes; (void)n_in; (void)out_size; (void)ws_size;
  const float* x  = (const float*)d_in[0];
  const float* Wq = (const float*)d_in[1];
  const float* bq = (const float*)d_in[2];
  const float* Wk = (const float*)d_in[3];
  const float* bk = (const float*)d_in[4];
  const float* Wv = (const float*)d_in[5];
  const float* bv = (const float*)d_in[6];
  const float* Wo = (const float*)d_in[7];
  const float* bo = (const float*)d_in[8];
  const float* hs = (const float*)d_in[9];

  char* ws = (char*)d_ws;
  ushort_t* xb  = (ushort_t*)ws;                      // 2M elems (4 MiB)
  ushort_t* wqb = (ushort_t*)(ws + 4 * 1024 * 1024);  // 64K elems each
  ushort_t* wkb = wqb + 65536;
  ushort_t* wvb = wkb + 65536;
  ushort_t* wob = wvb + 65536;
  ushort_t* qb  = wob + 65536;                        // 2M elems (4 MiB)
  ushort_t* kbb = qb + 2097152;
  ushort_t* vbb = kbb + 2097152;                      // V^T (B,H,Hd,S)
  float* opart  = (float*)(vbb + 2097152);            // 2x65536x32 f32 (16 MiB)
  float* lpart  = opart + 4194304;                    // 2x65536 f32 (512 KiB)
  ushort_t* hbb = xb;                                 // alias: x dead after proj

  cvt_all<<<2304, 256, 0, stream>>>(x, Wq, Wk, Wv, Wo, xb, wqb, wkb, wvb, wob);
  proj_qkv<<<dim3(4, 64, 3), 256, 0, stream>>>(xb, wqb, wkb, wvb, bq, bk, bv, qb, kbb, vbb);
  attn_kernel<<<dim3(32, 32), 512, 0, stream>>>(qb, kbb, vbb, opart, lpart);
  combine<<<1024, 256, 0, stream>>>(opart, lpart, hs, hbb);
  proj_out<<<dim3(4, 64), 256, 0, stream>>>(hbb, wob, bo, (float*)d_out);
}

// Round 15
// 60.348 us; speedup vs baseline: 1.0564x; 1.0564x over previous
//
#include <hip/hip_runtime.h>
#include <hip/hip_bf16.h>
#include <math.h>

#define B_ 4
#define S_ 2048
#define D_ 256
#define H_ 8
#define HD_ 32

typedef __attribute__((ext_vector_type(8))) short short8;
typedef __attribute__((ext_vector_type(4))) short short4v;
typedef __attribute__((ext_vector_type(4))) float floatx4;
typedef unsigned short ushort_t;
typedef unsigned int uint_t;

typedef union { unsigned u[2]; short4v v4; } PkU;

// v_cvt_pk_bf16_f32: pack 2 fp32 -> 2 bf16 (RNE), one instruction
#define CVT_PK(DST, LO, HI) \
  asm volatile("v_cvt_pk_bf16_f32 %0, %1, %2" : "=v"(DST) : "v"(LO), "v"(HI))

// D = A * B + D  (16x16x16 bf16 -> fp32 acc). Volatile: source order IS the
// emitted order. asm->asm VALU-write -> MFMA-read needs >=2 instr distance
// (round-6 lesson) -- honored by the 2-slot-lookahead pipeline below.
#define MFMA16(ACC, A, B) \
  asm volatile("v_mfma_f32_16x16x16_bf16 %0, %1, %2, %0" : "+v"(ACC) : "v"(A), "v"(B))

// round-to-nearest-even fp32 -> bf16 (scalar path)
__device__ __forceinline__ ushort_t f2bf(float f) {
  union { float f; unsigned u; } v; v.f = f;
  unsigned u = v.u;
  unsigned r = (u + 0x7FFFu + ((u >> 16) & 1u)) >> 16;
  return (ushort_t)r;
}

// fused fp32->bf16 conversion for x + all 4 weight matrices (one launch)
__global__ __launch_bounds__(256)
void cvt_all(const float* __restrict__ x,
             const float* __restrict__ wq, const float* __restrict__ wk,
             const float* __restrict__ wv, const float* __restrict__ wo,
             ushort_t* __restrict__ xb,
             ushort_t* __restrict__ wqb, ushort_t* __restrict__ wkb,
             ushort_t* __restrict__ wvb, ushort_t* __restrict__ wob)
{
  const int b = blockIdx.x;
  const float4* s; uint2* d; int i;
  if (b < 2048) {                       // x: 2M elems = 524288 float4
    s = (const float4*)x; d = (uint2*)xb; i = b * 256 + threadIdx.x;
  } else {                              // 4 weights: 16384 float4 each
    int r = b - 2048; int mm = r >> 6;
    s = (const float4*)(mm == 0 ? wq : mm == 1 ? wk : mm == 2 ? wv : wo);
    d = (uint2*)(mm == 0 ? wqb : mm == 1 ? wkb : mm == 2 ? wvb : wob);
    i = (r & 63) * 256 + threadIdx.x;
  }
  float4 f = s[i];
  uint2 o;
  CVT_PK(o.x, f.x, f.y);
  CVT_PK(o.y, f.z, f.w);
  d[i] = o;
}

// C = X @ W^T + b for Q,K,V (bf16). 128 rows/block; W-tile staged in LDS.
// Q pre-scaled by log2(e)/sqrt(Hd). Q,K -> (B,H,S,Hd); V -> TRANSPOSED (B,H,Hd,S).
__global__ __launch_bounds__(256)
void proj_qkv(const ushort_t* __restrict__ xb,
              const ushort_t* __restrict__ wq, const ushort_t* __restrict__ wk, const ushort_t* __restrict__ wv,
              const float* __restrict__ bq, const float* __restrict__ bk, const float* __restrict__ bv,
              ushort_t* __restrict__ qout, ushort_t* __restrict__ kout, ushort_t* __restrict__ vout)
{
  __shared__ __align__(16) ushort_t W_lds[64 * 264];   // 64 cols x 256 k, pad 264

  const int z = blockIdx.z;
  const ushort_t* wb = (z == 0) ? wq : (z == 1) ? wk : wv;
  const float* bias  = (z == 0) ? bq : (z == 1) ? bk : bv;

  const int t = threadIdx.x;
  const int l = t & 63;
  const int w = t >> 6;
  const int row0 = blockIdx.y * 128 + w * 16;   // rows row0 and row0+64
  const int col0 = blockIdx.x * 64;
  const int lr = l & 15, lg = l >> 4, lk = lg * 8;

  // ---- stage W-tile: thread t loads 128 B of row (t>>2) ----
  {
    const ushort_t* wsrc = wb + (col0 + (t >> 2)) * D_ + (t & 3) * 64;
    ushort_t* wdst = &W_lds[(t >> 2) * 264 + (t & 3) * 64];
#pragma unroll
    for (int i = 0; i < 8; ++i)
      *(uint4*)(wdst + i * 8) = *(const uint4*)(wsrc + i * 8);
  }
  __syncthreads();

  floatx4 acc[2][4] = {};
  const ushort_t* arow0 = xb + (row0 + lr) * D_ + lk;
  const ushort_t* arow1 = xb + (row0 + 64 + lr) * D_ + lk;
#pragma unroll
  for (int kk = 0; kk < D_; kk += 32) {
    short8 a0 = *(const short8*)(arow0 + kk);
    short8 a1 = *(const short8*)(arow1 + kk);
#pragma unroll
    for (int j = 0; j < 4; ++j) {
      short8 b = *(const short8*)&W_lds[(j * 16 + lr) * 264 + kk + lk];
      acc[0][j] = __builtin_amdgcn_mfma_f32_16x16x32_bf16(a0, b, acc[0][j], 0, 0, 0);
      acc[1][j] = __builtin_amdgcn_mfma_f32_16x16x32_bf16(a1, b, acc[1][j], 0, 0, 0);
    }
  }

  if (z == 2) {
    // V^T: (B,H,Hd,S); acc rows r -> consecutive s -> vectorized 8B store
#pragma unroll
    for (int rs = 0; rs < 2; ++rs)
#pragma unroll
      for (int j = 0; j < 4; ++j) {
        int c = col0 + j * 16 + lr;
        float bv_ = bias[c];
        int hh = c >> 5, d = c & 31;
        int i0 = row0 + rs * 64 + lg * 4;
        int bb = i0 >> 11, s0 = i0 & 2047;
        uint2 pv;
        CVT_PK(pv.x, acc[rs][j][0] + bv_, acc[rs][j][1] + bv_);
        CVT_PK(pv.y, acc[rs][j][2] + bv_, acc[rs][j][3] + bv_);
        *(uint2*)&vout[(((size_t)(bb * H_ + hh)) * HD_ + d) * S_ + s0] = pv;
      }
  } else {
    ushort_t* dst = (z == 0) ? qout : kout;
    const float qscale = (z == 0) ? 0.25503486f : 1.0f;  // log2(e)/sqrt(32)
#pragma unroll
    for (int rs = 0; rs < 2; ++rs)
#pragma unroll
      for (int j = 0; j < 4; ++j) {
        int c = col0 + j * 16 + lr;
        float bv_ = bias[c];
        int hh = c >> 5, d = c & 31;
#pragma unroll
        for (int rp = 0; rp < 2; ++rp) {
          int i = row0 + rs * 64 + lg * 4 + rp * 2;
          int bb = i >> 11, s = i & 2047;
          uint_t pr;
          CVT_PK(pr, (acc[rs][j][rp*2] + bv_) * qscale, (acc[rs][j][rp*2+1] + bv_) * qscale);
          size_t b0 = ((size_t)(bb * H_ + hh) * S_ + s) * HD_ + d;
          dst[b0]       = (ushort_t)(pr & 0xffffu);
          dst[b0 + HD_] = (ushort_t)(pr >> 16);
        }
      }
  }
}

// flash attention, no-max softmax. 512-thread blocks: 8 waves x 16 q-rows =
// 128 q-rows share each staged K/V tile (r13 proven structure, fastest).
// Round-15 change: lsum via per-lane VALU accumulation in the exp phase
// (r4-proven) instead of the ones-MFMA -- removes 8 of 24 volatile PV MFMAs
// per tile (-20% MFMA work, -33% PV chain length between barriers).
__global__ __launch_bounds__(512)
void attn_kernel(const ushort_t* __restrict__ qb, const ushort_t* __restrict__ kb,
                 const ushort_t* __restrict__ vtb, const float* __restrict__ head_scale,
                 ushort_t* __restrict__ hb)
{
  __shared__ __align__(16) ushort_t K_lds[2][128 * 40];   // [k][d] stride 40 (2-way free)
  __shared__ __align__(16) ushort_t Vt_lds[2][32 * 140];  // [d][k] stride 140 (2-way free)

  const int tid = threadIdx.x;
  const int l = tid & 63;
  const int w = tid >> 6;                      // 0..7
  // XCD swizzle: each XCD (f%8 under round-robin dispatch) owns 4 heads.
  const int f = blockIdx.y * 16 + blockIdx.x;  // 0..511
  const int qt = f >> 5;                       // 0..15 (128-row q tiles)
  const int bh = (f & 7) * 4 + ((f >> 3) & 3); // 0..31
  const int lr = l & 15;
  const int lg = l >> 4;

  const ushort_t* qp  = qb  + (size_t)bh * S_ * HD_;
  const ushort_t* kp  = kb  + (size_t)bh * S_ * HD_;
  const ushort_t* vtp = vtb + (size_t)bh * S_ * HD_;   // (Hd,S)

  const int q0 = qt * 128 + w * 16;
  short8 qfrag = *(const short8*)(qp + (q0 + lr) * HD_ + lg * 8);

  floatx4 oA = {}, oB = {};            // O^T accs
  float ls0 = 0.f, ls1 = 0.f, ls2 = 0.f, ls3 = 0.f;  // per-lane lsum partials

  const int kr = tid >> 2, kc = (tid & 3) * 8;    // K staging: 128 rows x 32, 1 uint4/thr
  const int vr = tid >> 4, vc = (tid & 15) * 8;   // V^T staging: 32 rows x 128, 1 uint4/thr

  const floatx4 zero4 = {0.f, 0.f, 0.f, 0.f};

  // prologue: stage tile 0
  uint4 kreg = *(const uint4*)(kp + kr * HD_ + kc);
  uint4 vreg = *(const uint4*)(vtp + vr * S_ + vc);
  *(uint4*)&K_lds[0][kr * 40 + kc] = kreg;
  {
    ushort_t* vd = &Vt_lds[0][vr * 140 + vc];   // row base 280B: 8B-aligned
    *(uint2*)(vd)     = make_uint2(vreg.x, vreg.y);
    *(uint2*)(vd + 4) = make_uint2(vreg.z, vreg.w);
  }

  int cur = 0;
  for (int t0 = 0; t0 < S_; t0 += 128) {
    __syncthreads();   // staged tile visible; everyone done reading buf^1

    // prefetch next tile into regs (wraps harmlessly on last iter)
    const int tn = (t0 + 128) & (S_ - 1);
    kreg = *(const uint4*)(kp + (tn + kr) * HD_ + kc);
    vreg = *(const uint4*)(vtp + vr * S_ + tn + vc);

    // ---- QK^T swapped, C=0: sv[s] = scores (log2 domain), 8 indep chains ----
    floatx4 sv[8];
#pragma unroll
    for (int s = 0; s < 8; ++s) {
      short8 kf = *(const short8*)&K_lds[cur][(s * 16 + lr) * 40 + lg * 8];
      sv[s] = __builtin_amdgcn_mfma_f32_16x16x32_bf16(kf, qfrag, zero4, 0, 0, 0);
    }

    // ---- software-pipelined softmax+PV (2-slot lookahead) ----
    PkU pk[8];
    __builtin_amdgcn_s_setprio(1);
    // pipeline prologue: slots 0,1 exp+lsum+pack
#pragma unroll
    for (int s = 0; s < 2; ++s) {
      sv[s][0] = __builtin_amdgcn_exp2f(sv[s][0]);
      sv[s][1] = __builtin_amdgcn_exp2f(sv[s][1]);
      sv[s][2] = __builtin_amdgcn_exp2f(sv[s][2]);
      sv[s][3] = __builtin_amdgcn_exp2f(sv[s][3]);
      ls0 += sv[s][0]; ls1 += sv[s][1]; ls2 += sv[s][2]; ls3 += sv[s][3];
    }
    CVT_PK(pk[0].u[0], sv[0][0], sv[0][1]);
    CVT_PK(pk[0].u[1], sv[0][2], sv[0][3]);
    CVT_PK(pk[1].u[0], sv[1][0], sv[1][1]);
    CVT_PK(pk[1].u[1], sv[1][2], sv[1][3]);
    // steady state: PV(s) interleaved with exp/lsum/pack(s+2)
#pragma unroll
    for (int s = 0; s < 8; ++s) {
      const int cb = s * 16 + lg * 4;
      short4v a0 = *(const short4v*)&Vt_lds[cur][lr * 140 + cb];
      short4v a1 = *(const short4v*)&Vt_lds[cur][(16 + lr) * 140 + cb];
      MFMA16(oA, a0, pk[s].v4);
      MFMA16(oB, a1, pk[s].v4);
      if (s + 2 < 8) {
        sv[s+2][0] = __builtin_amdgcn_exp2f(sv[s+2][0]);
        sv[s+2][1] = __builtin_amdgcn_exp2f(sv[s+2][1]);
        sv[s+2][2] = __builtin_amdgcn_exp2f(sv[s+2][2]);
        sv[s+2][3] = __builtin_amdgcn_exp2f(sv[s+2][3]);
        ls0 += sv[s+2][0]; ls1 += sv[s+2][1];
        ls2 += sv[s+2][2]; ls3 += sv[s+2][3];
        CVT_PK(pk[s+2].u[0], sv[s+2][0], sv[s+2][1]);
        CVT_PK(pk[s+2].u[1], sv[s+2][2], sv[s+2][3]);
      }
    }
    __builtin_amdgcn_s_setprio(0);

    // ---- store prefetched regs into the other buffer ----
    *(uint4*)&K_lds[cur ^ 1][kr * 40 + kc] = kreg;
    {
      ushort_t* vd = &Vt_lds[cur ^ 1][vr * 140 + vc];
      *(uint2*)(vd)     = make_uint2(vreg.x, vreg.y);
      *(uint2*)(vd + 4) = make_uint2(vreg.z, vreg.w);
    }
    cur ^= 1;
  }

  asm volatile("s_nop 7\n\ts_nop 7" :::);   // MFMA->VALU hazard guard
  // lsum: per-lane partials -> full per-q sum (butterfly over lg groups)
  float lsum = (ls0 + ls1) + (ls2 + ls3);
  lsum += __shfl_xor(lsum, 16, 64);
  lsum += __shfl_xor(lsum, 32, 64);
  const int bb = bh >> 3, hh = bh & 7;
  float inv = head_scale[hh] / lsum;
  const int sq = q0 + lr;
  size_t base = ((size_t)(bb * S_ + sq)) * D_ + hh * HD_;
  uint2 w0, w1;
  CVT_PK(w0.x, oA[0] * inv, oA[1] * inv);
  CVT_PK(w0.y, oA[2] * inv, oA[3] * inv);
  CVT_PK(w1.x, oB[0] * inv, oB[1] * inv);
  CVT_PK(w1.y, oB[2] * inv, oB[3] * inv);
  *(uint2*)&hb[base + lg * 4] = w0;
  *(uint2*)&hb[base + 16 + lg * 4] = w1;
}

// out = Hctx @ Wo^T + bo  (128 rows/block; Wo-tile staged in LDS, fp32 out)
__global__ __launch_bounds__(256)
void proj_out(const ushort_t* __restrict__ hbm, const ushort_t* __restrict__ wo,
              const float* __restrict__ bo, float* __restrict__ out)
{
  __shared__ __align__(16) ushort_t W_lds[64 * 264];

  const int t = threadIdx.x;
  const int l = t & 63;
  const int w = t >> 6;
  const int row0 = blockIdx.y * 128 + w * 16;   // rows row0 and row0+64
  const int col0 = blockIdx.x * 64;
  const int lr = l & 15, lg = l >> 4, lk = lg * 8;

  {
    const ushort_t* wsrc = wo + (col0 + (t >> 2)) * D_ + (t & 3) * 64;
    ushort_t* wdst = &W_lds[(t >> 2) * 264 + (t & 3) * 64];
#pragma unroll
    for (int i = 0; i < 8; ++i)
      *(uint4*)(wdst + i * 8) = *(const uint4*)(wsrc + i * 8);
  }
  __syncthreads();

  floatx4 acc[2][4] = {};
  const ushort_t* arow0 = hbm + (row0 + lr) * D_ + lk;
  const ushort_t* arow1 = hbm + (row0 + 64 + lr) * D_ + lk;
#pragma unroll
  for (int kk = 0; kk < D_; kk += 32) {
    short8 a0 = *(const short8*)(arow0 + kk);
    short8 a1 = *(const short8*)(arow1 + kk);
#pragma unroll
    for (int j = 0; j < 4; ++j) {
      short8 b = *(const short8*)&W_lds[(j * 16 + lr) * 264 + kk + lk];
      acc[0][j] = __builtin_amdgcn_mfma_f32_16x16x32_bf16(a0, b, acc[0][j], 0, 0, 0);
      acc[1][j] = __builtin_amdgcn_mfma_f32_16x16x32_bf16(a1, b, acc[1][j], 0, 0, 0);
    }
  }
#pragma unroll
  for (int rs = 0; rs < 2; ++rs)
#pragma unroll
    for (int j = 0; j < 4; ++j) {
      int c = col0 + j * 16 + lr;
      float bias = bo[c];
#pragma unroll
      for (int r = 0; r < 4; ++r) {
        int i = row0 + rs * 64 + lg * 4 + r;
        out[(size_t)i * D_ + c] = acc[rs][j][r] + bias;
      }
    }
}

extern "C" void kernel_launch(void* const* d_in, const int* in_sizes, int n_in,
                              void* d_out, int out_size, void* d_ws, size_t ws_size,
                              hipStream_t stream) {
  (void)in_sizes; (void)n_in; (void)out_size; (void)ws_size;
  const float* x  = (const float*)d_in[0];
  const float* Wq = (const float*)d_in[1];
  const float* bq = (const float*)d_in[2];
  const float* Wk = (const float*)d_in[3];
  const float* bk = (const float*)d_in[4];
  const float* Wv = (const float*)d_in[5];
  const float* bv = (const float*)d_in[6];
  const float* Wo = (const float*)d_in[7];
  const float* bo = (const float*)d_in[8];
  const float* hs = (const float*)d_in[9];

  char* ws = (char*)d_ws;
  ushort_t* xb  = (ushort_t*)ws;                      // 2M elems (4 MiB)
  ushort_t* wqb = (ushort_t*)(ws + 4 * 1024 * 1024);  // 64K elems each
  ushort_t* wkb = wqb + 65536;
  ushort_t* wvb = wkb + 65536;
  ushort_t* wob = wvb + 65536;
  ushort_t* qb  = wob + 65536;                        // 2M elems (4 MiB)
  ushort_t* kbb = qb + 2097152;
  ushort_t* vbb = kbb + 2097152;                      // V^T (B,H,Hd,S)
  ushort_t* hbb = xb;                                 // alias: x dead after proj

  cvt_all<<<2304, 256, 0, stream>>>(x, Wq, Wk, Wv, Wo, xb, wqb, wkb, wvb, wob);
  proj_qkv<<<dim3(4, 64, 3), 256, 0, stream>>>(xb, wqb, wkb, wvb, bq, bk, bv, qb, kbb, vbb);
  attn_kernel<<<dim3(16, 32), 512, 0, stream>>>(qb, kbb, vbb, hs, hbb);
  proj_out<<<dim3(4, 64), 256, 0, stream>>>(hbb, wob, bo, (float*)d_out);
}

// Round 16
// 58.357 us; speedup vs baseline: 1.0924x; 1.0341x over previous
//
#include <hip/hip_runtime.h>
#include <hip/hip_bf16.h>
#include <math.h>

#define B_ 4
#define S_ 2048
#define D_ 256
#define H_ 8
#define HD_ 32

typedef __attribute__((ext_vector_type(8))) short short8;
typedef __attribute__((ext_vector_type(4))) short short4v;
typedef __attribute__((ext_vector_type(4))) float floatx4;
typedef unsigned short ushort_t;
typedef unsigned int uint_t;

typedef union { unsigned u[2]; short4v v4; } PkU;

// v_cvt_pk_bf16_f32: pack 2 fp32 -> 2 bf16 (RNE), one instruction
#define CVT_PK(DST, LO, HI) \
  asm volatile("v_cvt_pk_bf16_f32 %0, %1, %2" : "=v"(DST) : "v"(LO), "v"(HI))

// D = A * B + D  (16x16x16 bf16 -> fp32 acc). Volatile: source order IS the
// emitted order. asm->asm VALU-write -> MFMA-read needs >=2 instr distance
// (round-6 lesson) -- honored by the 2-slot-lookahead pipeline below.
#define MFMA16(ACC, A, B) \
  asm volatile("v_mfma_f32_16x16x16_bf16 %0, %1, %2, %0" : "+v"(ACC) : "v"(A), "v"(B))

// round-to-nearest-even fp32 -> bf16 (scalar path)
__device__ __forceinline__ ushort_t f2bf(float f) {
  union { float f; unsigned u; } v; v.f = f;
  unsigned u = v.u;
  unsigned r = (u + 0x7FFFu + ((u >> 16) & 1u)) >> 16;
  return (ushort_t)r;
}

// fused fp32->bf16 conversion for x + all 4 weight matrices (one launch)
__global__ __launch_bounds__(256)
void cvt_all(const float* __restrict__ x,
             const float* __restrict__ wq, const float* __restrict__ wk,
             const float* __restrict__ wv, const float* __restrict__ wo,
             ushort_t* __restrict__ xb,
             ushort_t* __restrict__ wqb, ushort_t* __restrict__ wkb,
             ushort_t* __restrict__ wvb, ushort_t* __restrict__ wob)
{
  const int b = blockIdx.x;
  const float4* s; uint2* d; int i;
  if (b < 2048) {                       // x: 2M elems = 524288 float4
    s = (const float4*)x; d = (uint2*)xb; i = b * 256 + threadIdx.x;
  } else {                              // 4 weights: 16384 float4 each
    int r = b - 2048; int mm = r >> 6;
    s = (const float4*)(mm == 0 ? wq : mm == 1 ? wk : mm == 2 ? wv : wo);
    d = (uint2*)(mm == 0 ? wqb : mm == 1 ? wkb : mm == 2 ? wvb : wob);
    i = (r & 63) * 256 + threadIdx.x;
  }
  float4 f = s[i];
  uint2 o;
  CVT_PK(o.x, f.x, f.y);
  CVT_PK(o.y, f.z, f.w);
  d[i] = o;
}

// C = X @ W^T + b for Q,K,V (bf16). 128 rows/block; W-tile staged in LDS.
// Q pre-scaled by log2(e)/sqrt(Hd). Q,K -> (B,H,S,Hd); V -> TRANSPOSED (B,H,Hd,S).
__global__ __launch_bounds__(256)
void proj_qkv(const ushort_t* __restrict__ xb,
              const ushort_t* __restrict__ wq, const ushort_t* __restrict__ wk, const ushort_t* __restrict__ wv,
              const float* __restrict__ bq, const float* __restrict__ bk, const float* __restrict__ bv,
              ushort_t* __restrict__ qout, ushort_t* __restrict__ kout, ushort_t* __restrict__ vout)
{
  __shared__ __align__(16) ushort_t W_lds[64 * 264];   // 64 cols x 256 k, pad 264

  const int z = blockIdx.z;
  const ushort_t* wb = (z == 0) ? wq : (z == 1) ? wk : wv;
  const float* bias  = (z == 0) ? bq : (z == 1) ? bk : bv;

  const int t = threadIdx.x;
  const int l = t & 63;
  const int w = t >> 6;
  const int row0 = blockIdx.y * 128 + w * 16;   // rows row0 and row0+64
  const int col0 = blockIdx.x * 64;
  const int lr = l & 15, lg = l >> 4, lk = lg * 8;

  // ---- stage W-tile: thread t loads 128 B of row (t>>2) ----
  {
    const ushort_t* wsrc = wb + (col0 + (t >> 2)) * D_ + (t & 3) * 64;
    ushort_t* wdst = &W_lds[(t >> 2) * 264 + (t & 3) * 64];
#pragma unroll
    for (int i = 0; i < 8; ++i)
      *(uint4*)(wdst + i * 8) = *(const uint4*)(wsrc + i * 8);
  }
  __syncthreads();

  floatx4 acc[2][4] = {};
  const ushort_t* arow0 = xb + (row0 + lr) * D_ + lk;
  const ushort_t* arow1 = xb + (row0 + 64 + lr) * D_ + lk;
#pragma unroll
  for (int kk = 0; kk < D_; kk += 32) {
    short8 a0 = *(const short8*)(arow0 + kk);
    short8 a1 = *(const short8*)(arow1 + kk);
#pragma unroll
    for (int j = 0; j < 4; ++j) {
      short8 b = *(const short8*)&W_lds[(j * 16 + lr) * 264 + kk + lk];
      acc[0][j] = __builtin_amdgcn_mfma_f32_16x16x32_bf16(a0, b, acc[0][j], 0, 0, 0);
      acc[1][j] = __builtin_amdgcn_mfma_f32_16x16x32_bf16(a1, b, acc[1][j], 0, 0, 0);
    }
  }

  if (z == 2) {
    // V^T: (B,H,Hd,S); acc rows r -> consecutive s -> vectorized 8B store
#pragma unroll
    for (int rs = 0; rs < 2; ++rs)
#pragma unroll
      for (int j = 0; j < 4; ++j) {
        int c = col0 + j * 16 + lr;
        float bv_ = bias[c];
        int hh = c >> 5, d = c & 31;
        int i0 = row0 + rs * 64 + lg * 4;
        int bb = i0 >> 11, s0 = i0 & 2047;
        uint2 pv;
        CVT_PK(pv.x, acc[rs][j][0] + bv_, acc[rs][j][1] + bv_);
        CVT_PK(pv.y, acc[rs][j][2] + bv_, acc[rs][j][3] + bv_);
        *(uint2*)&vout[(((size_t)(bb * H_ + hh)) * HD_ + d) * S_ + s0] = pv;
      }
  } else {
    ushort_t* dst = (z == 0) ? qout : kout;
    const float qscale = (z == 0) ? 0.25503486f : 1.0f;  // log2(e)/sqrt(32)
#pragma unroll
    for (int rs = 0; rs < 2; ++rs)
#pragma unroll
      for (int j = 0; j < 4; ++j) {
        int c = col0 + j * 16 + lr;
        float bv_ = bias[c];
        int hh = c >> 5, d = c & 31;
#pragma unroll
        for (int rp = 0; rp < 2; ++rp) {
          int i = row0 + rs * 64 + lg * 4 + rp * 2;
          int bb = i >> 11, s = i & 2047;
          uint_t pr;
          CVT_PK(pr, (acc[rs][j][rp*2] + bv_) * qscale, (acc[rs][j][rp*2+1] + bv_) * qscale);
          size_t b0 = ((size_t)(bb * H_ + hh) * S_ + s) * HD_ + d;
          dst[b0]       = (ushort_t)(pr & 0xffffu);
          dst[b0 + HD_] = (ushort_t)(pr >> 16);
        }
      }
  }
}

// flash attention, no-max softmax. 512-thread blocks: 8 waves x 16 q-rows =
// 128 q-rows share each staged K/V tile (round-13 proven best: 58.6 us).
// Per-wave tile body = round-9's 2-slot-lookahead pipeline; lsum via
// ones-MFMA (r15 showed removing it does NOT help: latency-bound).
__global__ __launch_bounds__(512)
void attn_kernel(const ushort_t* __restrict__ qb, const ushort_t* __restrict__ kb,
                 const ushort_t* __restrict__ vtb, const float* __restrict__ head_scale,
                 ushort_t* __restrict__ hb)
{
  __shared__ __align__(16) ushort_t K_lds[2][128 * 40];   // [k][d] stride 40 (2-way free)
  __shared__ __align__(16) ushort_t Vt_lds[2][32 * 140];  // [d][k] stride 140 (2-way free)

  const int tid = threadIdx.x;
  const int l = tid & 63;
  const int w = tid >> 6;                      // 0..7
  // XCD swizzle: each XCD (f%8 under round-robin dispatch) owns 4 heads.
  const int f = blockIdx.y * 16 + blockIdx.x;  // 0..511
  const int qt = f >> 5;                       // 0..15 (128-row q tiles)
  const int bh = (f & 7) * 4 + ((f >> 3) & 3); // 0..31
  const int lr = l & 15;
  const int lg = l >> 4;

  const ushort_t* qp  = qb  + (size_t)bh * S_ * HD_;
  const ushort_t* kp  = kb  + (size_t)bh * S_ * HD_;
  const ushort_t* vtp = vtb + (size_t)bh * S_ * HD_;   // (Hd,S)

  const int q0 = qt * 128 + w * 16;
  short8 qfrag = *(const short8*)(qp + (q0 + lr) * HD_ + lg * 8);

  floatx4 oA = {}, oB = {}, oL = {};   // O^T accs + lsum acc (oL[0] meaningful)

  const int kr = tid >> 2, kc = (tid & 3) * 8;    // K staging: 128 rows x 32, 1 uint4/thr
  const int vr = tid >> 4, vc = (tid & 15) * 8;   // V^T staging: 32 rows x 128, 1 uint4/thr

  const short4v ones4 = {0x3F80, 0x3F80, 0x3F80, 0x3F80};  // bf16 1.0
  const floatx4 zero4 = {0.f, 0.f, 0.f, 0.f};

  // prologue: stage tile 0
  uint4 kreg = *(const uint4*)(kp + kr * HD_ + kc);
  uint4 vreg = *(const uint4*)(vtp + vr * S_ + vc);
  *(uint4*)&K_lds[0][kr * 40 + kc] = kreg;
  {
    ushort_t* vd = &Vt_lds[0][vr * 140 + vc];   // row base 280B: 8B-aligned
    *(uint2*)(vd)     = make_uint2(vreg.x, vreg.y);
    *(uint2*)(vd + 4) = make_uint2(vreg.z, vreg.w);
  }

  int cur = 0;
  for (int t0 = 0; t0 < S_; t0 += 128) {
    __syncthreads();   // staged tile visible; everyone done reading buf^1

    // prefetch next tile into regs (wraps harmlessly on last iter)
    const int tn = (t0 + 128) & (S_ - 1);
    kreg = *(const uint4*)(kp + (tn + kr) * HD_ + kc);
    vreg = *(const uint4*)(vtp + vr * S_ + tn + vc);

    // ---- QK^T swapped, C=0: sv[s] = scores (log2 domain), 8 indep chains ----
    floatx4 sv[8];
#pragma unroll
    for (int s = 0; s < 8; ++s) {
      short8 kf = *(const short8*)&K_lds[cur][(s * 16 + lr) * 40 + lg * 8];
      sv[s] = __builtin_amdgcn_mfma_f32_16x16x32_bf16(kf, qfrag, zero4, 0, 0, 0);
    }

    // ---- software-pipelined softmax+PV (2-slot lookahead) ----
    PkU pk[8];
    __builtin_amdgcn_s_setprio(1);
    // pipeline prologue: slots 0,1 exp+pack
#pragma unroll
    for (int s = 0; s < 2; ++s) {
      sv[s][0] = __builtin_amdgcn_exp2f(sv[s][0]);
      sv[s][1] = __builtin_amdgcn_exp2f(sv[s][1]);
      sv[s][2] = __builtin_amdgcn_exp2f(sv[s][2]);
      sv[s][3] = __builtin_amdgcn_exp2f(sv[s][3]);
    }
    CVT_PK(pk[0].u[0], sv[0][0], sv[0][1]);
    CVT_PK(pk[0].u[1], sv[0][2], sv[0][3]);
    CVT_PK(pk[1].u[0], sv[1][0], sv[1][1]);
    CVT_PK(pk[1].u[1], sv[1][2], sv[1][3]);
    // steady state: PV(s) interleaved with exp/pack(s+2)
#pragma unroll
    for (int s = 0; s < 8; ++s) {
      const int cb = s * 16 + lg * 4;
      short4v a0 = *(const short4v*)&Vt_lds[cur][lr * 140 + cb];
      short4v a1 = *(const short4v*)&Vt_lds[cur][(16 + lr) * 140 + cb];
      MFMA16(oA, a0, pk[s].v4);
      MFMA16(oB, a1, pk[s].v4);
      MFMA16(oL, ones4, pk[s].v4);
      if (s + 2 < 8) {
        sv[s+2][0] = __builtin_amdgcn_exp2f(sv[s+2][0]);
        sv[s+2][1] = __builtin_amdgcn_exp2f(sv[s+2][1]);
        sv[s+2][2] = __builtin_amdgcn_exp2f(sv[s+2][2]);
        sv[s+2][3] = __builtin_amdgcn_exp2f(sv[s+2][3]);
        CVT_PK(pk[s+2].u[0], sv[s+2][0], sv[s+2][1]);
        CVT_PK(pk[s+2].u[1], sv[s+2][2], sv[s+2][3]);
      }
    }
    __builtin_amdgcn_s_setprio(0);

    // ---- store prefetched regs into the other buffer ----
    *(uint4*)&K_lds[cur ^ 1][kr * 40 + kc] = kreg;
    {
      ushort_t* vd = &Vt_lds[cur ^ 1][vr * 140 + vc];
      *(uint2*)(vd)     = make_uint2(vreg.x, vreg.y);
      *(uint2*)(vd + 4) = make_uint2(vreg.z, vreg.w);
    }
    cur ^= 1;
  }

  asm volatile("s_nop 7\n\ts_nop 7" :::);   // MFMA->VALU hazard guard
  const int bb = bh >> 3, hh = bh & 7;
  float inv = head_scale[hh] / oL[0];       // oL[0] = complete per-q lsum
  const int sq = q0 + lr;
  size_t base = ((size_t)(bb * S_ + sq)) * D_ + hh * HD_;
  uint2 w0, w1;
  CVT_PK(w0.x, oA[0] * inv, oA[1] * inv);
  CVT_PK(w0.y, oA[2] * inv, oA[3] * inv);
  CVT_PK(w1.x, oB[0] * inv, oB[1] * inv);
  CVT_PK(w1.y, oB[2] * inv, oB[3] * inv);
  *(uint2*)&hb[base + lg * 4] = w0;
  *(uint2*)&hb[base + 16 + lg * 4] = w1;
}

// out = Hctx @ Wo^T + bo  (128 rows/block; Wo-tile staged in LDS, fp32 out)
__global__ __launch_bounds__(256)
void proj_out(const ushort_t* __restrict__ hbm, const ushort_t* __restrict__ wo,
              const float* __restrict__ bo, float* __restrict__ out)
{
  __shared__ __align__(16) ushort_t W_lds[64 * 264];

  const int t = threadIdx.x;
  const int l = t & 63;
  const int w = t >> 6;
  const int row0 = blockIdx.y * 128 + w * 16;   // rows row0 and row0+64
  const int col0 = blockIdx.x * 64;
  const int lr = l & 15, lg = l >> 4, lk = lg * 8;

  {
    const ushort_t* wsrc = wo + (col0 + (t >> 2)) * D_ + (t & 3) * 64;
    ushort_t* wdst = &W_lds[(t >> 2) * 264 + (t & 3) * 64];
#pragma unroll
    for (int i = 0; i < 8; ++i)
      *(uint4*)(wdst + i * 8) = *(const uint4*)(wsrc + i * 8);
  }
  __syncthreads();

  floatx4 acc[2][4] = {};
  const ushort_t* arow0 = hbm + (row0 + lr) * D_ + lk;
  const ushort_t* arow1 = hbm + (row0 + 64 + lr) * D_ + lk;
#pragma unroll
  for (int kk = 0; kk < D_; kk += 32) {
    short8 a0 = *(const short8*)(arow0 + kk);
    short8 a1 = *(const short8*)(arow1 + kk);
#pragma unroll
    for (int j = 0; j < 4; ++j) {
      short8 b = *(const short8*)&W_lds[(j * 16 + lr) * 264 + kk + lk];
      acc[0][j] = __builtin_amdgcn_mfma_f32_16x16x32_bf16(a0, b, acc[0][j], 0, 0, 0);
      acc[1][j] = __builtin_amdgcn_mfma_f32_16x16x32_bf16(a1, b, acc[1][j], 0, 0, 0);
    }
  }
#pragma unroll
  for (int rs = 0; rs < 2; ++rs)
#pragma unroll
    for (int j = 0; j < 4; ++j) {
      int c = col0 + j * 16 + lr;
      float bias = bo[c];
#pragma unroll
      for (int r = 0; r < 4; ++r) {
        int i = row0 + rs * 64 + lg * 4 + r;
        out[(size_t)i * D_ + c] = acc[rs][j][r] + bias;
      }
    }
}

extern "C" void kernel_launch(void* const* d_in, const int* in_sizes, int n_in,
                              void* d_out, int out_size, void* d_ws, size_t ws_size,
                              hipStream_t stream) {
  (void)in_sizes; (void)n_in; (void)out_size; (void)ws_size;
  const float* x  = (const float*)d_in[0];
  const float* Wq = (const float*)d_in[1];
  const float* bq = (const float*)d_in[2];
  const float* Wk = (const float*)d_in[3];
  const float* bk = (const float*)d_in[4];
  const float* Wv = (const float*)d_in[5];
  const float* bv = (const float*)d_in[6];
  const float* Wo = (const float*)d_in[7];
  const float* bo = (const float*)d_in[8];
  const float* hs = (const float*)d_in[9];

  char* ws = (char*)d_ws;
  ushort_t* xb  = (ushort_t*)ws;                      // 2M elems (4 MiB)
  ushort_t* wqb = (ushort_t*)(ws + 4 * 1024 * 1024);  // 64K elems each
  ushort_t* wkb = wqb + 65536;
  ushort_t* wvb = wkb + 65536;
  ushort_t* wob = wvb + 65536;
  ushort_t* qb  = wob + 65536;                        // 2M elems (4 MiB)
  ushort_t* kbb = qb + 2097152;
  ushort_t* vbb = kbb + 2097152;                      // V^T (B,H,Hd,S)
  ushort_t* hbb = xb;                                 // alias: x dead after proj

  cvt_all<<<2304, 256, 0, stream>>>(x, Wq, Wk, Wv, Wo, xb, wqb, wkb, wvb, wob);
  proj_qkv<<<dim3(4, 64, 3), 256, 0, stream>>>(xb, wqb, wkb, wvb, bq, bk, bv, qb, kbb, vbb);
  attn_kernel<<<dim3(16, 32), 512, 0, stream>>>(qb, kbb, vbb, hs, hbb);
  proj_out<<<dim3(4, 64), 256, 0, stream>>>(hbb, wob, bo, (float*)d_out);
}

// Round 18
// 58.176 us; speedup vs baseline: 1.0958x; 1.0031x over previous
//
#include <hip/hip_runtime.h>
#include <hip/hip_bf16.h>
#include <math.h>

#define B_ 4
#define S_ 2048
#define D_ 256
#define H_ 8
#define HD_ 32

typedef __attribute__((ext_vector_type(8))) short short8;
typedef __attribute__((ext_vector_type(4))) short short4v;
typedef __attribute__((ext_vector_type(4))) float floatx4;
typedef unsigned short ushort_t;
typedef unsigned int uint_t;

typedef union { unsigned u[2]; short4v v4; } PkU;

// v_cvt_pk_bf16_f32: pack 2 fp32 -> 2 bf16 (RNE), one instruction
#define CVT_PK(DST, LO, HI) \
  asm volatile("v_cvt_pk_bf16_f32 %0, %1, %2" : "=v"(DST) : "v"(LO), "v"(HI))

// D = A * B + D  (16x16x16 bf16 -> fp32 acc). Volatile: source order IS the
// emitted order. asm->asm VALU-write -> MFMA-read needs >=2 instr distance
// (round-6 lesson) -- honored by the 2-slot-lookahead pipeline below.
#define MFMA16(ACC, A, B) \
  asm volatile("v_mfma_f32_16x16x16_bf16 %0, %1, %2, %0" : "+v"(ACC) : "v"(A), "v"(B))

// round-to-nearest-even fp32 -> bf16 (scalar path)
__device__ __forceinline__ ushort_t f2bf(float f) {
  union { float f; unsigned u; } v; v.f = f;
  unsigned u = v.u;
  unsigned r = (u + 0x7FFFu + ((u >> 16) & 1u)) >> 16;
  return (ushort_t)r;
}

// fused fp32->bf16 conversion for x + all 4 weight matrices (one launch)
__global__ __launch_bounds__(256)
void cvt_all(const float* __restrict__ x,
             const float* __restrict__ wq, const float* __restrict__ wk,
             const float* __restrict__ wv, const float* __restrict__ wo,
             ushort_t* __restrict__ xb,
             ushort_t* __restrict__ wqb, ushort_t* __restrict__ wkb,
             ushort_t* __restrict__ wvb, ushort_t* __restrict__ wob)
{
  const int b = blockIdx.x;
  const float4* s; uint2* d; int i;
  if (b < 2048) {                       // x: 2M elems = 524288 float4
    s = (const float4*)x; d = (uint2*)xb; i = b * 256 + threadIdx.x;
  } else {                              // 4 weights: 16384 float4 each
    int r = b - 2048; int mm = r >> 6;
    s = (const float4*)(mm == 0 ? wq : mm == 1 ? wk : mm == 2 ? wv : wo);
    d = (uint2*)(mm == 0 ? wqb : mm == 1 ? wkb : mm == 2 ? wvb : wob);
    i = (r & 63) * 256 + threadIdx.x;
  }
  float4 f = s[i];
  uint2 o;
  CVT_PK(o.x, f.x, f.y);
  CVT_PK(o.y, f.z, f.w);
  d[i] = o;
}

// C = X @ W^T + b for Q,K,V (bf16). 128 rows/block; W-tile staged in LDS.
// Q pre-scaled by log2(e)/sqrt(Hd). Q,K -> (B,H,S,Hd); V -> TRANSPOSED (B,H,Hd,S).
__global__ __launch_bounds__(256)
void proj_qkv(const ushort_t* __restrict__ xb,
              const ushort_t* __restrict__ wq, const ushort_t* __restrict__ wk, const ushort_t* __restrict__ wv,
              const float* __restrict__ bq, const float* __restrict__ bk, const float* __restrict__ bv,
              ushort_t* __restrict__ qout, ushort_t* __restrict__ kout, ushort_t* __restrict__ vout)
{
  __shared__ __align__(16) ushort_t W_lds[64 * 264];   // 64 cols x 256 k, pad 264

  const int z = blockIdx.z;
  const ushort_t* wb = (z == 0) ? wq : (z == 1) ? wk : wv;
  const float* bias  = (z == 0) ? bq : (z == 1) ? bk : bv;

  const int t = threadIdx.x;
  const int l = t & 63;
  const int w = t >> 6;
  const int row0 = blockIdx.y * 128 + w * 16;   // rows row0 and row0+64
  const int col0 = blockIdx.x * 64;
  const int lr = l & 15, lg = l >> 4, lk = lg * 8;

  // ---- stage W-tile: thread t loads 128 B of row (t>>2) ----
  {
    const ushort_t* wsrc = wb + (col0 + (t >> 2)) * D_ + (t & 3) * 64;
    ushort_t* wdst = &W_lds[(t >> 2) * 264 + (t & 3) * 64];
#pragma unroll
    for (int i = 0; i < 8; ++i)
      *(uint4*)(wdst + i * 8) = *(const uint4*)(wsrc + i * 8);
  }
  __syncthreads();

  floatx4 acc[2][4] = {};
  const ushort_t* arow0 = xb + (row0 + lr) * D_ + lk;
  const ushort_t* arow1 = xb + (row0 + 64 + lr) * D_ + lk;
#pragma unroll
  for (int kk = 0; kk < D_; kk += 32) {
    short8 a0 = *(const short8*)(arow0 + kk);
    short8 a1 = *(const short8*)(arow1 + kk);
#pragma unroll
    for (int j = 0; j < 4; ++j) {
      short8 b = *(const short8*)&W_lds[(j * 16 + lr) * 264 + kk + lk];
      acc[0][j] = __builtin_amdgcn_mfma_f32_16x16x32_bf16(a0, b, acc[0][j], 0, 0, 0);
      acc[1][j] = __builtin_amdgcn_mfma_f32_16x16x32_bf16(a1, b, acc[1][j], 0, 0, 0);
    }
  }

  if (z == 2) {
    // V^T: (B,H,Hd,S); acc rows r -> consecutive s -> vectorized 8B store
#pragma unroll
    for (int rs = 0; rs < 2; ++rs)
#pragma unroll
      for (int j = 0; j < 4; ++j) {
        int c = col0 + j * 16 + lr;
        float bv_ = bias[c];
        int hh = c >> 5, d = c & 31;
        int i0 = row0 + rs * 64 + lg * 4;
        int bb = i0 >> 11, s0 = i0 & 2047;
        uint2 pv;
        CVT_PK(pv.x, acc[rs][j][0] + bv_, acc[rs][j][1] + bv_);
        CVT_PK(pv.y, acc[rs][j][2] + bv_, acc[rs][j][3] + bv_);
        *(uint2*)&vout[(((size_t)(bb * H_ + hh)) * HD_ + d) * S_ + s0] = pv;
      }
  } else {
    ushort_t* dst = (z == 0) ? qout : kout;
    const float qscale = (z == 0) ? 0.25503486f : 1.0f;  // log2(e)/sqrt(32)
#pragma unroll
    for (int rs = 0; rs < 2; ++rs)
#pragma unroll
      for (int j = 0; j < 4; ++j) {
        int c = col0 + j * 16 + lr;
        float bv_ = bias[c];
        int hh = c >> 5, d = c & 31;
#pragma unroll
        for (int rp = 0; rp < 2; ++rp) {
          int i = row0 + rs * 64 + lg * 4 + rp * 2;
          int bb = i >> 11, s = i & 2047;
          uint_t pr;
          CVT_PK(pr, (acc[rs][j][rp*2] + bv_) * qscale, (acc[rs][j][rp*2+1] + bv_) * qscale);
          size_t b0 = ((size_t)(bb * H_ + hh) * S_ + s) * HD_ + d;
          dst[b0]       = (ushort_t)(pr & 0xffffu);
          dst[b0 + HD_] = (ushort_t)(pr >> 16);
        }
      }
  }
}

// flash attention, no-max softmax. 512-thread blocks: 8 waves x 16 q-rows =
// 128 q-rows share each staged K/V tile (round-13 proven best: 58.4-58.6 us,
// reproduced twice). Per-wave tile body = round-9's 2-slot-lookahead
// pipeline; lsum via ones-MFMA. KVBLK=128 (r17's 256 failed correctness;
// r15 showed fewer MFMAs don't help; structure is latency-bound plateau).
__global__ __launch_bounds__(512)
void attn_kernel(const ushort_t* __restrict__ qb, const ushort_t* __restrict__ kb,
                 const ushort_t* __restrict__ vtb, const float* __restrict__ head_scale,
                 ushort_t* __restrict__ hb)
{
  __shared__ __align__(16) ushort_t K_lds[2][128 * 40];   // [k][d] stride 40 (2-way free)
  __shared__ __align__(16) ushort_t Vt_lds[2][32 * 140];  // [d][k] stride 140 (2-way free)

  const int tid = threadIdx.x;
  const int l = tid & 63;
  const int w = tid >> 6;                      // 0..7
  // XCD swizzle: each XCD (f%8 under round-robin dispatch) owns 4 heads.
  const int f = blockIdx.y * 16 + blockIdx.x;  // 0..511
  const int qt = f >> 5;                       // 0..15 (128-row q tiles)
  const int bh = (f & 7) * 4 + ((f >> 3) & 3); // 0..31
  const int lr = l & 15;
  const int lg = l >> 4;

  const ushort_t* qp  = qb  + (size_t)bh * S_ * HD_;
  const ushort_t* kp  = kb  + (size_t)bh * S_ * HD_;
  const ushort_t* vtp = vtb + (size_t)bh * S_ * HD_;   // (Hd,S)

  const int q0 = qt * 128 + w * 16;
  short8 qfrag = *(const short8*)(qp + (q0 + lr) * HD_ + lg * 8);

  floatx4 oA = {}, oB = {}, oL = {};   // O^T accs + lsum acc (oL[0] meaningful)

  const int kr = tid >> 2, kc = (tid & 3) * 8;    // K staging: 128 rows x 32, 1 uint4/thr
  const int vr = tid >> 4, vc = (tid & 15) * 8;   // V^T staging: 32 rows x 128, 1 uint4/thr

  const short4v ones4 = {0x3F80, 0x3F80, 0x3F80, 0x3F80};  // bf16 1.0
  const floatx4 zero4 = {0.f, 0.f, 0.f, 0.f};

  // prologue: stage tile 0
  uint4 kreg = *(const uint4*)(kp + kr * HD_ + kc);
  uint4 vreg = *(const uint4*)(vtp + vr * S_ + vc);
  *(uint4*)&K_lds[0][kr * 40 + kc] = kreg;
  {
    ushort_t* vd = &Vt_lds[0][vr * 140 + vc];   // row base 280B: 8B-aligned
    *(uint2*)(vd)     = make_uint2(vreg.x, vreg.y);
    *(uint2*)(vd + 4) = make_uint2(vreg.z, vreg.w);
  }

  int cur = 0;
  for (int t0 = 0; t0 < S_; t0 += 128) {
    __syncthreads();   // staged tile visible; everyone done reading buf^1

    // prefetch next tile into regs (wraps harmlessly on last iter)
    const int tn = (t0 + 128) & (S_ - 1);
    kreg = *(const uint4*)(kp + (tn + kr) * HD_ + kc);
    vreg = *(const uint4*)(vtp + vr * S_ + tn + vc);

    // ---- QK^T swapped, C=0: sv[s] = scores (log2 domain), 8 indep chains ----
    floatx4 sv[8];
#pragma unroll
    for (int s = 0; s < 8; ++s) {
      short8 kf = *(const short8*)&K_lds[cur][(s * 16 + lr) * 40 + lg * 8];
      sv[s] = __builtin_amdgcn_mfma_f32_16x16x32_bf16(kf, qfrag, zero4, 0, 0, 0);
    }

    // ---- software-pipelined softmax+PV (2-slot lookahead) ----
    PkU pk[8];
    __builtin_amdgcn_s_setprio(1);
    // pipeline prologue: slots 0,1 exp+pack
#pragma unroll
    for (int s = 0; s < 2; ++s) {
      sv[s][0] = __builtin_amdgcn_exp2f(sv[s][0]);
      sv[s][1] = __builtin_amdgcn_exp2f(sv[s][1]);
      sv[s][2] = __builtin_amdgcn_exp2f(sv[s][2]);
      sv[s][3] = __builtin_amdgcn_exp2f(sv[s][3]);
    }
    CVT_PK(pk[0].u[0], sv[0][0], sv[0][1]);
    CVT_PK(pk[0].u[1], sv[0][2], sv[0][3]);
    CVT_PK(pk[1].u[0], sv[1][0], sv[1][1]);
    CVT_PK(pk[1].u[1], sv[1][2], sv[1][3]);
    // steady state: PV(s) interleaved with exp/pack(s+2)
#pragma unroll
    for (int s = 0; s < 8; ++s) {
      const int cb = s * 16 + lg * 4;
      short4v a0 = *(const short4v*)&Vt_lds[cur][lr * 140 + cb];
      short4v a1 = *(const short4v*)&Vt_lds[cur][(16 + lr) * 140 + cb];
      MFMA16(oA, a0, pk[s].v4);
      MFMA16(oB, a1, pk[s].v4);
      MFMA16(oL, ones4, pk[s].v4);
      if (s + 2 < 8) {
        sv[s+2][0] = __builtin_amdgcn_exp2f(sv[s+2][0]);
        sv[s+2][1] = __builtin_amdgcn_exp2f(sv[s+2][1]);
        sv[s+2][2] = __builtin_amdgcn_exp2f(sv[s+2][2]);
        sv[s+2][3] = __builtin_amdgcn_exp2f(sv[s+2][3]);
        CVT_PK(pk[s+2].u[0], sv[s+2][0], sv[s+2][1]);
        CVT_PK(pk[s+2].u[1], sv[s+2][2], sv[s+2][3]);
      }
    }
    __builtin_amdgcn_s_setprio(0);

    // ---- store prefetched regs into the other buffer ----
    *(uint4*)&K_lds[cur ^ 1][kr * 40 + kc] = kreg;
    {
      ushort_t* vd = &Vt_lds[cur ^ 1][vr * 140 + vc];
      *(uint2*)(vd)     = make_uint2(vreg.x, vreg.y);
      *(uint2*)(vd + 4) = make_uint2(vreg.z, vreg.w);
    }
    cur ^= 1;
  }

  asm volatile("s_nop 7\n\ts_nop 7" :::);   // MFMA->VALU hazard guard
  const int bb = bh >> 3, hh = bh & 7;
  float inv = head_scale[hh] / oL[0];       // oL[0] = complete per-q lsum
  const int sq = q0 + lr;
  size_t base = ((size_t)(bb * S_ + sq)) * D_ + hh * HD_;
  uint2 w0, w1;
  CVT_PK(w0.x, oA[0] * inv, oA[1] * inv);
  CVT_PK(w0.y, oA[2] * inv, oA[3] * inv);
  CVT_PK(w1.x, oB[0] * inv, oB[1] * inv);
  CVT_PK(w1.y, oB[2] * inv, oB[3] * inv);
  *(uint2*)&hb[base + lg * 4] = w0;
  *(uint2*)&hb[base + 16 + lg * 4] = w1;
}

// out = Hctx @ Wo^T + bo  (128 rows/block; Wo-tile staged in LDS, fp32 out)
__global__ __launch_bounds__(256)
void proj_out(const ushort_t* __restrict__ hbm, const ushort_t* __restrict__ wo,
              const float* __restrict__ bo, float* __restrict__ out)
{
  __shared__ __align__(16) ushort_t W_lds[64 * 264];

  const int t = threadIdx.x;
  const int l = t & 63;
  const int w = t >> 6;
  const int row0 = blockIdx.y * 128 + w * 16;   // rows row0 and row0+64
  const int col0 = blockIdx.x * 64;
  const int lr = l & 15, lg = l >> 4, lk = lg * 8;

  {
    const ushort_t* wsrc = wo + (col0 + (t >> 2)) * D_ + (t & 3) * 64;
    ushort_t* wdst = &W_lds[(t >> 2) * 264 + (t & 3) * 64];
#pragma unroll
    for (int i = 0; i < 8; ++i)
      *(uint4*)(wdst + i * 8) = *(const uint4*)(wsrc + i * 8);
  }
  __syncthreads();

  floatx4 acc[2][4] = {};
  const ushort_t* arow0 = hbm + (row0 + lr) * D_ + lk;
  const ushort_t* arow1 = hbm + (row0 + 64 + lr) * D_ + lk;
#pragma unroll
  for (int kk = 0; kk < D_; kk += 32) {
    short8 a0 = *(const short8*)(arow0 + kk);
    short8 a1 = *(const short8*)(arow1 + kk);
#pragma unroll
    for (int j = 0; j < 4; ++j) {
      short8 b = *(const short8*)&W_lds[(j * 16 + lr) * 264 + kk + lk];
      acc[0][j] = __builtin_amdgcn_mfma_f32_16x16x32_bf16(a0, b, acc[0][j], 0, 0, 0);
      acc[1][j] = __builtin_amdgcn_mfma_f32_16x16x32_bf16(a1, b, acc[1][j], 0, 0, 0);
    }
  }
#pragma unroll
  for (int rs = 0; rs < 2; ++rs)
#pragma unroll
    for (int j = 0; j < 4; ++j) {
      int c = col0 + j * 16 + lr;
      float bias = bo[c];
#pragma unroll
      for (int r = 0; r < 4; ++r) {
        int i = row0 + rs * 64 + lg * 4 + r;
        out[(size_t)i * D_ + c] = acc[rs][j][r] + bias;
      }
    }
}

extern "C" void kernel_launch(void* const* d_in, const int* in_sizes, int n_in,
                              void* d_out, int out_size, void* d_ws, size_t ws_size,
                              hipStream_t stream) {
  (void)in_sizes; (void)n_in; (void)out_size; (void)ws_size;
  const float* x  = (const float*)d_in[0];
  const float* Wq = (const float*)d_in[1];
  const float* bq = (const float*)d_in[2];
  const float* Wk = (const float*)d_in[3];
  const float* bk = (const float*)d_in[4];
  const float* Wv = (const float*)d_in[5];
  const float* bv = (const float*)d_in[6];
  const float* Wo = (const float*)d_in[7];
  const float* bo = (const float*)d_in[8];
  const float* hs = (const float*)d_in[9];

  char* ws = (char*)d_ws;
  ushort_t* xb  = (ushort_t*)ws;                      // 2M elems (4 MiB)
  ushort_t* wqb = (ushort_t*)(ws + 4 * 1024 * 1024);  // 64K elems each
  ushort_t* wkb = wqb + 65536;
  ushort_t* wvb = wkb + 65536;
  ushort_t* wob = wvb + 65536;
  ushort_t* qb  = wob + 65536;                        // 2M elems (4 MiB)
  ushort_t* kbb = qb + 2097152;
  ushort_t* vbb = kbb + 2097152;                      // V^T (B,H,Hd,S)
  ushort_t* hbb = xb;                                 // alias: x dead after proj

  cvt_all<<<2304, 256, 0, stream>>>(x, Wq, Wk, Wv, Wo, xb, wqb, wkb, wvb, wob);
  proj_qkv<<<dim3(4, 64, 3), 256, 0, stream>>>(xb, wqb, wkb, wvb, bq, bk, bv, qb, kbb, vbb);
  attn_kernel<<<dim3(16, 32), 512, 0, stream>>>(qb, kbb, vbb, hs, hbb);
  proj_out<<<dim3(4, 64), 256, 0, stream>>>(hbb, wob, bo, (float*)d_out);
}